// Round 2
// baseline (2625.080 us; speedup 1.0000x reference)
//
#include <hip/hip_runtime.h>

// Problem constants: N=4, C=64, H=128, W=128, KS=3, dilations {1,3,5}
// Inputs: x[4,64,128,128] f32, y[same], gen_w[1728,64], gen_b[1728],
//         fuse_w[64,256,3,3], fuse_b[64]. Out: [4,64,128,128] f32.

// Workspace layout (float offsets)
#define OFF_GW3 0u
#define SZ_GW3  (192u*64u*9u)          // gen_w transposed: [comb][cc][tap]
#define OFF_FW2 (OFF_GW3 + SZ_GW3)     // fuse_w transposed: [(ic*9+k)*64 + oc]
#define SZ_FW2  (256u*9u*64u)
#define OFF_CAT (OFF_FW2 + SZ_FW2)     // cat (branches only): [n][192][128][128]
// total floats = 110592 + 147456 + 12582912 = 12840960 (~51.4 MB)

__global__ void k_prep_gen(const float* __restrict__ gen_w,
                           float* __restrict__ ws) {
    int idx = blockIdx.x * 256 + threadIdx.x;
    if (idx >= 1728 * 64) return;
    int o = idx >> 6, cc = idx & 63;
    int comb = o / 9, tap = o % 9;
    ws[OFF_GW3 + comb * 576 + cc * 9 + tap] = gen_w[o * 64 + cc];
}

__global__ void k_prep_fuse(const float* __restrict__ fuse_w,
                            float* __restrict__ ws) {
    int idx = blockIdx.x * 256 + threadIdx.x;   // over 64*2304
    if (idx >= 64 * 2304) return;
    int oc = idx / 2304;
    int r  = idx % 2304;                        // ic*9 + k
    ws[OFF_FW2 + r * 64 + oc] = fuse_w[idx];
}

// Fused kernel-generation (per-pixel matvec, broadcast-GEMV form) +
// 3-branch dilated depthwise conv.
// Grid: (W/64, H, N), block 256 (4 waves). lane = w pixel; wave-uniform comb
// loop; weights via wave-uniform s_load; y held in 64 VGPRs per lane.
__global__ __launch_bounds__(256) void k_gen_ddpm(const float* __restrict__ x,
                                                  const float* __restrict__ y,
                                                  const float* __restrict__ gw3,
                                                  const float* __restrict__ gen_b,
                                                  float* __restrict__ cat) {
    const int w0   = blockIdx.x * 64;
    const int h    = blockIdx.y;
    const int n    = blockIdx.z;
    const int lane = threadIdx.x & 63;
    const int wv   = __builtin_amdgcn_readfirstlane(threadIdx.x >> 6);
    const int w    = w0 + lane;

    // Hoist this pixel's y column (64 channels) into registers. Coalesced:
    // each load is 64 lanes x 4B contiguous.
    float yr[64];
    const float* yb = y + (((size_t)n * 64) * 128 + h) * 128 + w;
#pragma unroll
    for (int cc = 0; cc < 64; ++cc) yr[cc] = yb[cc * 16384];

    // Each wave owns 48 of the 192 (branch, channel) combos.
    for (int i = 0; i < 48; ++i) {
        const int comb = wv * 48 + i;          // wave-uniform
        const int c    = comb & 63;
        const int bi   = comb >> 6;
        const int d    = 2 * bi + 1;           // dilation 1,3,5
        const float* __restrict__ gwr = gw3 + comb * 576;

        float kk[9];
#pragma unroll
        for (int tap = 0; tap < 9; ++tap) kk[tap] = gen_b[comb * 9 + tap];

        // kk[tap] = gen_b + sum_cc gw[comb][cc][tap] * y[cc][pixel]
        // gwr[] is wave-uniform -> scalar loads; yr[] static-indexed VGPRs.
#pragma unroll
        for (int cc = 0; cc < 64; ++cc) {
            const float yv = yr[cc];
#pragma unroll
            for (int tap = 0; tap < 9; ++tap)
                kk[tap] = fmaf(gwr[cc * 9 + tap], yv, kk[tap]);
        }

        // Depthwise apply at this pixel with zero padding.
        const float* __restrict__ xc = x + (((size_t)n * 64 + c) * 128) * 128;
        float acc = 0.f;
#pragma unroll
        for (int ki = 0; ki < 3; ++ki) {
            const int hh = h + (ki - 1) * d;   // uniform bound check
            if (hh < 0 || hh >= 128) continue;
            const float* __restrict__ xr = xc + hh * 128;
#pragma unroll
            for (int kj = 0; kj < 3; ++kj) {
                const int ww = w + (kj - 1) * d;
                if (ww >= 0 && ww < 128)
                    acc = fmaf(kk[ki * 3 + kj], xr[ww], acc);
            }
        }
        cat[(((size_t)n * 192 + comb) * 128 + h) * 128 + w] = acc;
    }
}

// Dense 3x3 conv 256->64 over cat (=[x | branches]) + bias.
// Grid: (W/64, H, N), block 256 (4 waves). lane = w, wave q owns oc q*16..q*16+15.
__global__ __launch_bounds__(256) void k_fuse(const float* __restrict__ x,
                                              const float* __restrict__ ws,
                                              const float* __restrict__ fuse_b,
                                              float* __restrict__ out) {
    __shared__ float xl[16][3][68];
    const int w0   = blockIdx.x * 64;
    const int h    = blockIdx.y;
    const int n    = blockIdx.z;
    const int t    = threadIdx.x;
    const int lane = t & 63;
    const int oc0  = __builtin_amdgcn_readfirstlane((t >> 6) * 16);
    const float* fw2 = ws + OFF_FW2;
    const float* cat = ws + OFF_CAT;

    float acc[16];
#pragma unroll
    for (int j = 0; j < 16; ++j) acc[j] = 0.f;

    for (int ic0 = 0; ic0 < 256; ic0 += 16) {
        __syncthreads();
        for (int e = t; e < 16 * 3 * 66; e += 256) {
            int icw = e / 198;
            int rem = e % 198;
            int r   = rem / 66;
            int col = rem % 66;
            int ic  = ic0 + icw;
            int hh  = h + r - 1;
            int wwp = w0 + col - 1;
            float v = 0.f;
            if (hh >= 0 && hh < 128 && wwp >= 0 && wwp < 128) {
                const float* src = (ic < 64)
                    ? (x   + (((size_t)n * 64  + ic)        * 128) * 128)
                    : (cat + (((size_t)n * 192 + (ic - 64)) * 128) * 128);
                v = src[hh * 128 + wwp];
            }
            xl[icw][r][col] = v;
        }
        __syncthreads();

#pragma unroll 1
        for (int icw = 0; icw < 16; ++icw) {
            const int base9 = (ic0 + icw) * 9;
#pragma unroll
            for (int kh = 0; kh < 3; ++kh) {
                float xv[3];
                xv[0] = xl[icw][kh][lane];
                xv[1] = xl[icw][kh][lane + 1];
                xv[2] = xl[icw][kh][lane + 2];
#pragma unroll
                for (int kw = 0; kw < 3; ++kw) {
                    const float* fp = fw2 + (base9 + kh * 3 + kw) * 64 + oc0;
                    float fv[16];
                    *(float4*)&fv[0]  = ((const float4*)fp)[0];
                    *(float4*)&fv[4]  = ((const float4*)fp)[1];
                    *(float4*)&fv[8]  = ((const float4*)fp)[2];
                    *(float4*)&fv[12] = ((const float4*)fp)[3];
                    const float xvv = xv[kw];
#pragma unroll
                    for (int j = 0; j < 16; ++j)
                        acc[j] = fmaf(fv[j], xvv, acc[j]);
                }
            }
        }
    }

#pragma unroll
    for (int j = 0; j < 16; ++j) {
        int oc = oc0 + j;
        out[(((size_t)n * 64 + oc) * 128 + h) * 128 + w0 + lane] = acc[j] + fuse_b[oc];
    }
}

extern "C" void kernel_launch(void* const* d_in, const int* in_sizes, int n_in,
                              void* d_out, int out_size, void* d_ws, size_t ws_size,
                              hipStream_t stream) {
    const float* x      = (const float*)d_in[0];
    const float* y      = (const float*)d_in[1];
    const float* gen_w  = (const float*)d_in[2];
    const float* gen_b  = (const float*)d_in[3];
    const float* fuse_w = (const float*)d_in[4];
    const float* fuse_b = (const float*)d_in[5];
    float* out = (float*)d_out;
    float* ws  = (float*)d_ws;

    k_prep_gen<<<dim3((1728 * 64 + 255) / 256), dim3(256), 0, stream>>>(gen_w, ws);
    k_prep_fuse<<<dim3((64 * 2304 + 255) / 256), dim3(256), 0, stream>>>(fuse_w, ws);
    k_gen_ddpm<<<dim3(128 / 64, 128, 4), dim3(256), 0, stream>>>(
        x, y, ws + OFF_GW3, gen_b, ws + OFF_CAT);
    k_fuse<<<dim3(128 / 64, 128, 4), dim3(256), 0, stream>>>(x, ws, fuse_b, out);
}

// Round 3
// 565.244 us; speedup vs baseline: 4.6442x; 4.6442x over previous
//
#include <hip/hip_runtime.h>

// Problem: N=4, C=64, H=W=128, KS=3, dilations {1,3,5}
// x[4,64,128,128] f32, y[same], gen_w[1728,64], gen_b[1728],
// fuse_w[64,256,3,3], fuse_b[64] -> out[4,64,128,128] f32.

using f32x4 = __attribute__((ext_vector_type(4))) float;
using s16x8 = __attribute__((ext_vector_type(8))) short;

// Workspace layout (float offsets)
#define OFF_WPK 0u                      // gen_w pre-packed MFMA A-frags (bf16):
                                        // [tap][tile12][ks2][lane64][8] = 110592 bf16
#define OFF_FW2 55296u                  // fuse_w transposed: [(ic*9+k)*64 + oc]
#define OFF_CAT 202752u                 // cat branches: [n][192][128][128]
// total floats = 202752 + 12582912 = 12785664 (~51.1 MB)

__device__ __forceinline__ unsigned short f2bf(float f) {
    unsigned u = __builtin_bit_cast(unsigned, f);
    u = (u + 0x7fffu + ((u >> 16) & 1u)) >> 16;   // RNE
    return (unsigned short)u;
}

// Pre-pack gen_w into per-lane MFMA A-fragment order (bf16).
// A-frag for 16x16x32: lane l holds A[row = l&15][k = ks*32 + (l>>4)*8 + j], j=0..7.
__global__ void k_prep_wpk(const float* __restrict__ gen_w,
                           unsigned short* __restrict__ wpk) {
    int idx = blockIdx.x * 256 + threadIdx.x;
    if (idx >= 9 * 12 * 2 * 64) return;
    int lane = idx & 63;
    int r = idx >> 6;
    int ks = r & 1; r >>= 1;
    int tile = r % 12, tap = r / 12;
    int comb = tile * 16 + (lane & 15);
    int cc0  = ks * 32 + (lane >> 4) * 8;
    const float* src = gen_w + (size_t)(comb * 9 + tap) * 64 + cc0;
    unsigned short v[8];
#pragma unroll
    for (int j = 0; j < 8; ++j) v[j] = f2bf(src[j]);
    *(s16x8*)(wpk + (size_t)idx * 8) = *(const s16x8*)v;
}

__global__ void k_prep_fuse(const float* __restrict__ fuse_w,
                            float* __restrict__ ws) {
    int idx = blockIdx.x * 256 + threadIdx.x;   // over 64*2304
    if (idx >= 64 * 2304) return;
    int oc = idx / 2304;
    int r  = idx % 2304;                        // ic*9 + k
    ws[OFF_FW2 + r * 64 + oc] = fuse_w[idx];
}

// MFMA kernel-generation + depthwise apply.
// Grid (2,128,4), block 256 (4 waves). Block = one 64-px w-strip at (h,n).
// GEMM per tap: K[192 combs][64 px] = W_tap[192x64] @ Y[64x64], bf16 MFMA.
// Wave wv owns comb row-tiles {3wv,3wv+1,3wv+2} (= combs 48wv..48wv+47):
// K round-trips a wave-private LDS slab, then lane=px depthwise accumulates.
__global__ __launch_bounds__(256) void k_gen_mfma(
    const float* __restrict__ x, const float* __restrict__ y,
    const unsigned short* __restrict__ wpk, const float* __restrict__ gen_b,
    float* __restrict__ cat)
{
    __shared__ float K_lds[192][68];            // stride 68 -> 2-way banks (free)
    __shared__ __align__(16) unsigned Yt[2048]; // Y^T bf16 [px][cc], XOR-swizzled

    const int w0 = blockIdx.x * 64;
    const int h  = blockIdx.y;
    const int n  = blockIdx.z;
    const int t  = threadIdx.x;
    const int lane = t & 63;
    const int wv = t >> 6;                      // uniform
    const int q = lane >> 4, col = lane & 15;

    // ---- stage Y^T in LDS (bf16 pairs, swizzle byte ^ ((px&7)<<4)) ----
    {
        const float* yb = y + (size_t)n * 64 * 16384 + h * 128 + w0 + lane;
#pragma unroll
        for (int p = 0; p < 8; ++p) {
            int cp = wv * 8 + p;                // cc pair 0..31
            float a = yb[(size_t)(2 * cp) * 16384];
            float b = yb[(size_t)(2 * cp + 1) * 16384];
            unsigned v = (unsigned)f2bf(a) | ((unsigned)f2bf(b) << 16);
            unsigned byte = ((unsigned)(lane * 128 + cp * 4)) ^ (((unsigned)(lane & 7)) << 4);
            Yt[byte >> 2] = v;
        }
    }
    __syncthreads();

    // ---- B-fragments (Y), tap-invariant: lane holds B[k=ks*32+q*8+j][px tile col] ----
    s16x8 bfr[4][2];
#pragma unroll
    for (int ctp = 0; ctp < 4; ++ctp)
#pragma unroll
        for (int ks = 0; ks < 2; ++ks) {
            int px = ctp * 16 + col;
            unsigned byte = ((unsigned)(px * 128 + (ks * 32 + q * 8) * 2)) ^
                            (((unsigned)(px & 7)) << 4);
            bfr[ctp][ks] = *(const s16x8*)((const char*)Yt + byte);
        }

    const int tile0 = wv * 3;
    const float* xn = x + (size_t)n * 64 * 16384;

    float acc[48];
#pragma unroll
    for (int i = 0; i < 48; ++i) acc[i] = 0.f;

#pragma unroll 1
    for (int tap = 0; tap < 9; ++tap) {
        const unsigned short* wp = wpk + ((size_t)(tap * 12 + tile0) * 2 * 64 + lane) * 8;
#pragma unroll
        for (int rt = 0; rt < 3; ++rt) {
            const int combr = (tile0 + rt) * 16 + q * 4;   // C row base for this lane
            f32x4 cinit;
#pragma unroll
            for (int r = 0; r < 4; ++r) cinit[r] = gen_b[(combr + r) * 9 + tap];
            s16x8 a0 = *(const s16x8*)(wp + (size_t)(rt * 2 + 0) * 512);
            s16x8 a1 = *(const s16x8*)(wp + (size_t)(rt * 2 + 1) * 512);
#pragma unroll
            for (int ctp = 0; ctp < 4; ++ctp) {
                f32x4 kf = __builtin_amdgcn_mfma_f32_16x16x32_bf16(a0, bfr[ctp][0], cinit, 0, 0, 0);
                kf = __builtin_amdgcn_mfma_f32_16x16x32_bf16(a1, bfr[ctp][1], kf, 0, 0, 0);
#pragma unroll
                for (int r = 0; r < 4; ++r)
                    K_lds[combr + r][ctp * 16 + col] = kf[r];   // wave-private rows
            }
        }

        // ---- depthwise accumulate for this tap (lane = px, coalesced x) ----
        const int ti = tap / 3, tj = tap % 3;
#pragma unroll
        for (int i = 0; i < 48; ++i) {
            const int comb = wv * 48 + i;       // uniform
            const int bi = comb >> 6;
            const int c  = comb & 63;
            const int d  = 2 * bi + 1;
            const int hh = h + (ti - 1) * d;
            if (hh < 0 || hh >= 128) continue;  // uniform (zero-pad)
            const int ww = w0 + lane + (tj - 1) * d;
            float xv = ((unsigned)ww < 128u) ? xn[(size_t)c * 16384 + hh * 128 + ww] : 0.f;
            acc[i] = fmaf(K_lds[comb][lane], xv, acc[i]);
        }
    }

    float* cb = cat + (size_t)n * 192 * 16384 + h * 128 + w0 + lane;
#pragma unroll
    for (int i = 0; i < 48; ++i)
        cb[(size_t)(wv * 48 + i) * 16384] = acc[i];
}

// Dense 3x3 conv 256->64 over [x | cat] + bias (unchanged from R1).
__global__ __launch_bounds__(256) void k_fuse(const float* __restrict__ x,
                                              const float* __restrict__ ws,
                                              const float* __restrict__ fuse_b,
                                              float* __restrict__ out) {
    __shared__ float xl[16][3][68];
    const int w0   = blockIdx.x * 64;
    const int h    = blockIdx.y;
    const int n    = blockIdx.z;
    const int t    = threadIdx.x;
    const int lane = t & 63;
    const int oc0  = __builtin_amdgcn_readfirstlane((t >> 6) * 16);
    const float* fw2 = ws + OFF_FW2;
    const float* cat = ws + OFF_CAT;

    float acc[16];
#pragma unroll
    for (int j = 0; j < 16; ++j) acc[j] = 0.f;

    for (int ic0 = 0; ic0 < 256; ic0 += 16) {
        __syncthreads();
        for (int e = t; e < 16 * 3 * 66; e += 256) {
            int icw = e / 198;
            int rem = e % 198;
            int r   = rem / 66;
            int col = rem % 66;
            int ic  = ic0 + icw;
            int hh  = h + r - 1;
            int wwp = w0 + col - 1;
            float v = 0.f;
            if (hh >= 0 && hh < 128 && wwp >= 0 && wwp < 128) {
                const float* src = (ic < 64)
                    ? (x   + (((size_t)n * 64  + ic)        * 128) * 128)
                    : (cat + (((size_t)n * 192 + (ic - 64)) * 128) * 128);
                v = src[hh * 128 + wwp];
            }
            xl[icw][r][col] = v;
        }
        __syncthreads();

#pragma unroll 1
        for (int icw = 0; icw < 16; ++icw) {
            const int base9 = (ic0 + icw) * 9;
#pragma unroll
            for (int kh = 0; kh < 3; ++kh) {
                float xv[3];
                xv[0] = xl[icw][kh][lane];
                xv[1] = xl[icw][kh][lane + 1];
                xv[2] = xl[icw][kh][lane + 2];
#pragma unroll
                for (int kw = 0; kw < 3; ++kw) {
                    const float* fp = fw2 + (base9 + kh * 3 + kw) * 64 + oc0;
                    float fv[16];
                    *(float4*)&fv[0]  = ((const float4*)fp)[0];
                    *(float4*)&fv[4]  = ((const float4*)fp)[1];
                    *(float4*)&fv[8]  = ((const float4*)fp)[2];
                    *(float4*)&fv[12] = ((const float4*)fp)[3];
                    const float xvv = xv[kw];
#pragma unroll
                    for (int j = 0; j < 16; ++j)
                        acc[j] = fmaf(fv[j], xvv, acc[j]);
                }
            }
        }
    }

#pragma unroll
    for (int j = 0; j < 16; ++j) {
        int oc = oc0 + j;
        out[(((size_t)n * 64 + oc) * 128 + h) * 128 + w0 + lane] = acc[j] + fuse_b[oc];
    }
}

extern "C" void kernel_launch(void* const* d_in, const int* in_sizes, int n_in,
                              void* d_out, int out_size, void* d_ws, size_t ws_size,
                              hipStream_t stream) {
    const float* x      = (const float*)d_in[0];
    const float* y      = (const float*)d_in[1];
    const float* gen_w  = (const float*)d_in[2];
    const float* gen_b  = (const float*)d_in[3];
    const float* fuse_w = (const float*)d_in[4];
    const float* fuse_b = (const float*)d_in[5];
    float* out = (float*)d_out;
    float* ws  = (float*)d_ws;

    k_prep_wpk<<<dim3((13824 + 255) / 256), dim3(256), 0, stream>>>(
        gen_w, (unsigned short*)(ws + OFF_WPK));
    k_prep_fuse<<<dim3((64 * 2304 + 255) / 256), dim3(256), 0, stream>>>(fuse_w, ws);
    k_gen_mfma<<<dim3(2, 128, 4), dim3(256), 0, stream>>>(
        x, y, (const unsigned short*)(ws + OFF_WPK), gen_b, ws + OFF_CAT);
    k_fuse<<<dim3(128 / 64, 128, 4), dim3(256), 0, stream>>>(x, ws, fuse_b, out);
}

// Round 4
// 350.775 us; speedup vs baseline: 7.4837x; 1.6114x over previous
//
#include <hip/hip_runtime.h>

// Problem: N=4, C=64, H=W=128, KS=3, dilations {1,3,5}
// x[4,64,128,128] f32, y[same], gen_w[1728,64], gen_b[1728],
// fuse_w[64,256,3,3], fuse_b[64] -> out[4,64,128,128] f32.

using f32x4 = __attribute__((ext_vector_type(4))) float;
using s16x8 = __attribute__((ext_vector_type(8))) short;

// Workspace layout (float offsets)
#define OFF_WPK 0u        // gen_w A-frags bf16 [tap][tile12][ks2][lane][8] = 110592 bf16
#define OFF_FW3 55296u    // fuse_w A-frags bf16 [g9][chunk4][ks2][rt4][lane][8] = 147456 bf16
#define OFF_CAT 202752u   // cat branches: [n][192][128][128] f32
// total floats = 202752 + 12582912 = 12785664 (~51.1 MB)

__device__ __forceinline__ unsigned short f2bf(float f) {
    unsigned u = __builtin_bit_cast(unsigned, f);
    u = (u + 0x7fffu + ((u >> 16) & 1u)) >> 16;   // RNE
    return (unsigned short)u;
}

// Pre-pack gen_w into per-lane MFMA A-fragment order (bf16).
__global__ void k_prep_wpk(const float* __restrict__ gen_w,
                           unsigned short* __restrict__ wpk) {
    int idx = blockIdx.x * 256 + threadIdx.x;
    if (idx >= 9 * 12 * 2 * 64) return;
    int lane = idx & 63;
    int r = idx >> 6;
    int ks = r & 1; r >>= 1;
    int tile = r % 12, tap = r / 12;
    int comb = tile * 16 + (lane & 15);
    int cc0  = ks * 32 + (lane >> 4) * 8;
    const float* src = gen_w + (size_t)(comb * 9 + tap) * 64 + cc0;
    unsigned short v[8];
#pragma unroll
    for (int j = 0; j < 8; ++j) v[j] = f2bf(src[j]);
    *(s16x8*)(wpk + (size_t)idx * 8) = *(const s16x8*)v;
}

// Pre-pack fuse_w into per-lane MFMA A-fragment order (bf16).
// frag_id = ((g*4 + chunk)*2 + ks)*4 + rt ; oc = rt*16 + (lane&15),
// ic = chunk*64 + ks*32 + (lane>>4)*8 + j ; src = fuse_w[oc][ic][g]
__global__ void k_prep_fw3(const float* __restrict__ fuse_w,
                           unsigned short* __restrict__ fw3) {
    int idx = blockIdx.x * 256 + threadIdx.x;
    if (idx >= 288 * 64) return;
    int lane = idx & 63;
    int f = idx >> 6;
    int rt = f & 3; f >>= 2;
    int ks = f & 1; f >>= 1;
    int chunk = f & 3;
    int g = f >> 2;
    int oc = rt * 16 + (lane & 15);
    int ic = chunk * 64 + ks * 32 + (lane >> 4) * 8;
    const float* src = fuse_w + (size_t)oc * 2304 + (size_t)ic * 9 + g;
    unsigned short v[8];
#pragma unroll
    for (int j = 0; j < 8; ++j) v[j] = f2bf(src[j * 9]);
    *(s16x8*)(fw3 + (size_t)idx * 8) = *(const s16x8*)v;
}

// MFMA kernel-generation + depthwise apply (unchanged from R3).
__global__ __launch_bounds__(256) void k_gen_mfma(
    const float* __restrict__ x, const float* __restrict__ y,
    const unsigned short* __restrict__ wpk, const float* __restrict__ gen_b,
    float* __restrict__ cat)
{
    __shared__ float K_lds[192][68];
    __shared__ __align__(16) unsigned Yt[2048];

    const int w0 = blockIdx.x * 64;
    const int h  = blockIdx.y;
    const int n  = blockIdx.z;
    const int t  = threadIdx.x;
    const int lane = t & 63;
    const int wv = t >> 6;
    const int q = lane >> 4, col = lane & 15;

    {
        const float* yb = y + (size_t)n * 64 * 16384 + h * 128 + w0 + lane;
#pragma unroll
        for (int p = 0; p < 8; ++p) {
            int cp = wv * 8 + p;
            float a = yb[(size_t)(2 * cp) * 16384];
            float b = yb[(size_t)(2 * cp + 1) * 16384];
            unsigned v = (unsigned)f2bf(a) | ((unsigned)f2bf(b) << 16);
            unsigned byte = ((unsigned)(lane * 128 + cp * 4)) ^ (((unsigned)(lane & 7)) << 4);
            Yt[byte >> 2] = v;
        }
    }
    __syncthreads();

    s16x8 bfr[4][2];
#pragma unroll
    for (int ctp = 0; ctp < 4; ++ctp)
#pragma unroll
        for (int ks = 0; ks < 2; ++ks) {
            int px = ctp * 16 + col;
            unsigned byte = ((unsigned)(px * 128 + (ks * 32 + q * 8) * 2)) ^
                            (((unsigned)(px & 7)) << 4);
            bfr[ctp][ks] = *(const s16x8*)((const char*)Yt + byte);
        }

    const int tile0 = wv * 3;
    const float* xn = x + (size_t)n * 64 * 16384;

    float acc[48];
#pragma unroll
    for (int i = 0; i < 48; ++i) acc[i] = 0.f;

#pragma unroll 1
    for (int tap = 0; tap < 9; ++tap) {
        const unsigned short* wp = wpk + ((size_t)(tap * 12 + tile0) * 2 * 64 + lane) * 8;
#pragma unroll
        for (int rt = 0; rt < 3; ++rt) {
            const int combr = (tile0 + rt) * 16 + q * 4;
            f32x4 cinit;
#pragma unroll
            for (int r = 0; r < 4; ++r) cinit[r] = gen_b[(combr + r) * 9 + tap];
            s16x8 a0 = *(const s16x8*)(wp + (size_t)(rt * 2 + 0) * 512);
            s16x8 a1 = *(const s16x8*)(wp + (size_t)(rt * 2 + 1) * 512);
#pragma unroll
            for (int ctp = 0; ctp < 4; ++ctp) {
                f32x4 kf = __builtin_amdgcn_mfma_f32_16x16x32_bf16(a0, bfr[ctp][0], cinit, 0, 0, 0);
                kf = __builtin_amdgcn_mfma_f32_16x16x32_bf16(a1, bfr[ctp][1], kf, 0, 0, 0);
#pragma unroll
                for (int r = 0; r < 4; ++r)
                    K_lds[combr + r][ctp * 16 + col] = kf[r];
            }
        }

        const int ti = tap / 3, tj = tap % 3;
#pragma unroll
        for (int i = 0; i < 48; ++i) {
            const int comb = wv * 48 + i;
            const int bi = comb >> 6;
            const int c  = comb & 63;
            const int d  = 2 * bi + 1;
            const int hh = h + (ti - 1) * d;
            if (hh < 0 || hh >= 128) continue;
            const int ww = w0 + lane + (tj - 1) * d;
            float xv = ((unsigned)ww < 128u) ? xn[(size_t)c * 16384 + hh * 128 + ww] : 0.f;
            acc[i] = fmaf(K_lds[comb][lane], xv, acc[i]);
        }
    }

    float* cb = cat + (size_t)n * 192 * 16384 + h * 128 + w0 + lane;
#pragma unroll
    for (int i = 0; i < 48; ++i)
        cb[(size_t)(wv * 48 + i) * 16384] = acc[i];
}

// Fuse conv as bf16 MFMA GEMM: out[64 oc][64 px] per block.
// Grid (2,128,4), block 256 (4 waves; wave = 16-px column tile ctp).
// K = 256 ch x 9 taps, processed as 4 chunks x 9 (kh,kw) x 2 K-steps.
__global__ __launch_bounds__(256) void k_fuse_mfma(
    const float* __restrict__ x, const float* __restrict__ cat,
    const unsigned short* __restrict__ fw3, const float* __restrict__ fuse_b,
    float* __restrict__ out)
{
    __shared__ __align__(16) unsigned Xt[3 * 66 * 32];  // [r][px66][cp32] swizzled, 25.3KB

    const int w0 = blockIdx.x * 64;
    const int h  = blockIdx.y;
    const int n  = blockIdx.z;
    const int t  = threadIdx.x;
    const int lane = t & 63;
    const int ctp = t >> 6;            // wave-uniform px tile
    const int col = lane & 15, q = lane >> 4;

    f32x4 acc[4];
#pragma unroll
    for (int rt = 0; rt < 4; ++rt) acc[rt] = (f32x4){0.f, 0.f, 0.f, 0.f};

#pragma unroll 1
    for (int chunk = 0; chunk < 4; ++chunk) {
        __syncthreads();
        const float* src = (chunk == 0)
            ? x   + (size_t)n * 64 * 16384
            : cat + ((size_t)n * 192 + (chunk - 1) * 64) * 16384;
        // stage [3 rows][66 px][64 ch] as bf16 pairs, swizzled
        for (int e = t; e < 6336; e += 256) {
            int cp  = e / 198;
            int rem = e % 198;
            int r   = rem / 66;
            int px  = rem % 66;
            int hh  = h + r - 1;
            int wp  = w0 + px - 1;
            unsigned v = 0;
            if ((unsigned)hh < 128u && (unsigned)wp < 128u) {
                const float* p = src + (size_t)(2 * cp) * 16384 + hh * 128 + wp;
                v = (unsigned)f2bf(p[0]) | ((unsigned)f2bf(p[16384]) << 16);
            }
            Xt[((r * 66 + px) * 32 + cp) ^ ((px & 7) << 2)] = v;
        }
        __syncthreads();

#pragma unroll
        for (int g = 0; g < 9; ++g) {
            const int kh = g / 3, kw = g % 3;
#pragma unroll
            for (int ks = 0; ks < 2; ++ks) {
                const int col_t = ctp * 16 + col + kw;
                unsigned byte = (unsigned)(((kh * 66 + col_t) * 32 + ks * 16 + q * 4) << 2)
                                ^ ((unsigned)(col_t & 7) << 4);
                s16x8 bf = *(const s16x8*)((const char*)Xt + byte);
                const unsigned short* ap =
                    fw3 + ((size_t)((((g * 4 + chunk) * 2 + ks) * 4) * 64 + lane)) * 8;
#pragma unroll
                for (int rt = 0; rt < 4; ++rt) {
                    s16x8 af = *(const s16x8*)(ap + (size_t)rt * 512);
                    acc[rt] = __builtin_amdgcn_mfma_f32_16x16x32_bf16(af, bf, acc[rt], 0, 0, 0);
                }
            }
        }
    }

    const int px = w0 + ctp * 16 + col;
#pragma unroll
    for (int rt = 0; rt < 4; ++rt) {
        f32x4 fb = *(const f32x4*)(fuse_b + rt * 16 + q * 4);
#pragma unroll
        for (int r = 0; r < 4; ++r) {
            int oc = rt * 16 + q * 4 + r;
            out[((size_t)n * 64 + oc) * 16384 + h * 128 + px] = acc[rt][r] + fb[r];
        }
    }
}

extern "C" void kernel_launch(void* const* d_in, const int* in_sizes, int n_in,
                              void* d_out, int out_size, void* d_ws, size_t ws_size,
                              hipStream_t stream) {
    const float* x      = (const float*)d_in[0];
    const float* y      = (const float*)d_in[1];
    const float* gen_w  = (const float*)d_in[2];
    const float* gen_b  = (const float*)d_in[3];
    const float* fuse_w = (const float*)d_in[4];
    const float* fuse_b = (const float*)d_in[5];
    float* out = (float*)d_out;
    float* ws  = (float*)d_ws;

    k_prep_wpk<<<dim3((13824 + 255) / 256), dim3(256), 0, stream>>>(
        gen_w, (unsigned short*)(ws + OFF_WPK));
    k_prep_fw3<<<dim3((288 * 64 + 255) / 256), dim3(256), 0, stream>>>(
        fuse_w, (unsigned short*)(ws + OFF_FW3));
    k_gen_mfma<<<dim3(2, 128, 4), dim3(256), 0, stream>>>(
        x, y, (const unsigned short*)(ws + OFF_WPK), gen_b, ws + OFF_CAT);
    k_fuse_mfma<<<dim3(2, 128, 4), dim3(256), 0, stream>>>(
        x, ws + OFF_CAT, (const unsigned short*)(ws + OFF_FW3), fuse_b, out);
}

// Round 5
// 162.368 us; speedup vs baseline: 16.1675x; 2.1604x over previous
//
#include <hip/hip_runtime.h>

// Problem: N=4, C=64, H=W=128, KS=3, dilations {1,3,5}
// x[4,64,128,128] f32, y[same], gen_w[1728,64], gen_b[1728],
// fuse_w[64,256,3,3], fuse_b[64] -> out[4,64,128,128] f32.

using f32x4 = __attribute__((ext_vector_type(4))) float;
using s16x8 = __attribute__((ext_vector_type(8))) short;

// Workspace layout (float offsets)
#define OFF_WPK 0u        // gen_w A-frags bf16 [tap][tile12][ks2][lane][8] = 110592 bf16
#define OFF_FW3 55296u    // fuse_w A-frags bf16 [g9][chunk4][ks2][rt4][lane][8] = 147456 bf16
#define OFF_GBP 129024u   // gen_b fragment-order f32 [tap][tile12][row16] = 1728 f32
#define OFF_CAT 202752u   // cat branches: [n][192][128][128] f32
// total floats = 202752 + 12582912 = 12785664 (~51.1 MB)

__device__ __forceinline__ unsigned short f2bf(float f) {
    unsigned u = __builtin_bit_cast(unsigned, f);
    u = (u + 0x7fffu + ((u >> 16) & 1u)) >> 16;   // RNE
    return (unsigned short)u;
}

// Pre-pack gen_w into per-lane MFMA A-fragment order (bf16).
__global__ void k_prep_wpk(const float* __restrict__ gen_w,
                           unsigned short* __restrict__ wpk) {
    int idx = blockIdx.x * 256 + threadIdx.x;
    if (idx >= 9 * 12 * 2 * 64) return;
    int lane = idx & 63;
    int r = idx >> 6;
    int ks = r & 1; r >>= 1;
    int tile = r % 12, tap = r / 12;
    int comb = tile * 16 + (lane & 15);
    int cc0  = ks * 32 + (lane >> 4) * 8;
    const float* src = gen_w + (size_t)(comb * 9 + tap) * 64 + cc0;
    unsigned short v[8];
#pragma unroll
    for (int j = 0; j < 8; ++j) v[j] = f2bf(src[j]);
    *(s16x8*)(wpk + (size_t)idx * 8) = *(const s16x8*)v;
}

// gen_b in fragment order: gbp[(tap*12+tile)*16 + row] = gen_b[(tile*16+row)*9 + tap]
__global__ void k_prep_gb(const float* __restrict__ gen_b,
                          float* __restrict__ gbp) {
    int idx = blockIdx.x * 256 + threadIdx.x;
    if (idx >= 1728) return;
    int row = idx & 15;
    int r = idx >> 4;
    int tile = r % 12, tap = r / 12;
    gbp[idx] = gen_b[(tile * 16 + row) * 9 + tap];
}

// Pre-pack fuse_w into per-lane MFMA A-fragment order (bf16).
__global__ void k_prep_fw3(const float* __restrict__ fuse_w,
                           unsigned short* __restrict__ fw3) {
    int idx = blockIdx.x * 256 + threadIdx.x;
    if (idx >= 288 * 64) return;
    int lane = idx & 63;
    int f = idx >> 6;
    int rt = f & 3; f >>= 2;
    int ks = f & 1; f >>= 1;
    int chunk = f & 3;
    int g = f >> 2;
    int oc = rt * 16 + (lane & 15);
    int ic = chunk * 64 + ks * 32 + (lane >> 4) * 8;
    const float* src = fuse_w + (size_t)oc * 2304 + (size_t)ic * 9 + g;
    unsigned short v[8];
#pragma unroll
    for (int j = 0; j < 8; ++j) v[j] = f2bf(src[j * 9]);
    *(s16x8*)(fw3 + (size_t)idx * 8) = *(const s16x8*)v;
}

// MFMA kernel-generation + in-register depthwise apply (no K round-trip).
// Grid (2,128,4), block 256 (4 waves). Wave wv owns comb tiles tile0..tile0+2
// (tile = 16 combs, single branch each since bi = tile>>2). Per tap:
// C-frag = MFMA(W_tap, Y) directly consumed: lane holds 4 combs x 1 px.
__global__ __launch_bounds__(256, 3) void k_gen_mfma(
    const float* __restrict__ x, const float* __restrict__ y,
    const unsigned short* __restrict__ wpk, const float* __restrict__ gbp,
    float* __restrict__ cat)
{
    __shared__ __align__(16) unsigned Yt[2048]; // Y^T bf16 [px][cc], swizzled (8KB)

    const int w0 = blockIdx.x * 64;
    const int h  = blockIdx.y;
    const int n  = blockIdx.z;
    const int t  = threadIdx.x;
    const int lane = t & 63;
    const int wv = t >> 6;                      // uniform
    const int q = lane >> 4, col = lane & 15;

    // ---- stage Y^T in LDS (bf16 pairs, swizzle byte ^ ((px&7)<<4)) ----
    {
        const float* yb = y + (size_t)n * 64 * 16384 + h * 128 + w0 + lane;
#pragma unroll
        for (int p = 0; p < 8; ++p) {
            int cp = wv * 8 + p;
            float a = yb[(size_t)(2 * cp) * 16384];
            float b = yb[(size_t)(2 * cp + 1) * 16384];
            unsigned v = (unsigned)f2bf(a) | ((unsigned)f2bf(b) << 16);
            unsigned byte = ((unsigned)(lane * 128 + cp * 4)) ^ (((unsigned)(lane & 7)) << 4);
            Yt[byte >> 2] = v;
        }
    }
    __syncthreads();

    // ---- B-fragments (Y), tap-invariant ----
    s16x8 bfr[4][2];
#pragma unroll
    for (int ctp = 0; ctp < 4; ++ctp)
#pragma unroll
        for (int ks = 0; ks < 2; ++ks) {
            int px = ctp * 16 + col;
            unsigned byte = ((unsigned)(px * 128 + (ks * 32 + q * 8) * 2)) ^
                            (((unsigned)(px & 7)) << 4);
            bfr[ctp][ks] = *(const s16x8*)((const char*)Yt + byte);
        }

    const int tile0 = wv * 3;
    const float* xn = x + (size_t)n * 64 * 16384;

    float acc[3][4][4];                         // [rt][ctp][r]
#pragma unroll
    for (int rt = 0; rt < 3; ++rt)
#pragma unroll
        for (int ctp = 0; ctp < 4; ++ctp)
#pragma unroll
            for (int r = 0; r < 4; ++r) acc[rt][ctp][r] = 0.f;

#pragma unroll 1
    for (int tap = 0; tap < 9; ++tap) {
        const int ti = tap / 3, tj = tap % 3;
        const unsigned short* wp = wpk + ((size_t)(tap * 12 + tile0) * 2 * 64 + lane) * 8;
#pragma unroll
        for (int rt = 0; rt < 3; ++rt) {
            const int tile = tile0 + rt;        // uniform
            const int bi = tile >> 2;           // branch for this whole tile
            const int d  = 2 * bi + 1;
            const int hh = h + (ti - 1) * d;    // uniform
            const int cb = (tile & 3) * 16 + q * 4;   // channel base for this lane

            f32x4 cinit = *(const f32x4*)(gbp + (size_t)(tap * 12 + tile) * 16 + q * 4);
            s16x8 a0 = *(const s16x8*)(wp + (size_t)(rt * 2 + 0) * 512);
            s16x8 a1 = *(const s16x8*)(wp + (size_t)(rt * 2 + 1) * 512);
#pragma unroll
            for (int ctp = 0; ctp < 4; ++ctp) {
                f32x4 kf = __builtin_amdgcn_mfma_f32_16x16x32_bf16(a0, bfr[ctp][0], cinit, 0, 0, 0);
                kf = __builtin_amdgcn_mfma_f32_16x16x32_bf16(a1, bfr[ctp][1], kf, 0, 0, 0);
                if (hh >= 0 && hh < 128) {      // uniform (zero-pad row)
                    const int ww = w0 + ctp * 16 + col + (tj - 1) * d;
                    const bool inw = ((unsigned)ww < 128u);
                    const float* xr = xn + hh * 128 + ww;
#pragma unroll
                    for (int r = 0; r < 4; ++r) {
                        float xv = inw ? xr[(size_t)(cb + r) * 16384] : 0.f;
                        acc[rt][ctp][r] = fmaf(kf[r], xv, acc[rt][ctp][r]);
                    }
                }
            }
        }
    }

    // ---- write cat: lane writes 4 comb-rows x 16-contig px per (rt,ctp) ----
    float* cb0 = cat + (size_t)n * 192 * 16384 + h * 128;
#pragma unroll
    for (int rt = 0; rt < 3; ++rt) {
        const int combr = (tile0 + rt) * 16 + q * 4;
#pragma unroll
        for (int ctp = 0; ctp < 4; ++ctp) {
            const int px = w0 + ctp * 16 + col;
#pragma unroll
            for (int r = 0; r < 4; ++r)
                cb0[(size_t)(combr + r) * 16384 + px] = acc[rt][ctp][r];
        }
    }
}

// Fuse conv as bf16 MFMA GEMM (unchanged from R4).
__global__ __launch_bounds__(256) void k_fuse_mfma(
    const float* __restrict__ x, const float* __restrict__ cat,
    const unsigned short* __restrict__ fw3, const float* __restrict__ fuse_b,
    float* __restrict__ out)
{
    __shared__ __align__(16) unsigned Xt[3 * 66 * 32];

    const int w0 = blockIdx.x * 64;
    const int h  = blockIdx.y;
    const int n  = blockIdx.z;
    const int t  = threadIdx.x;
    const int lane = t & 63;
    const int ctp = t >> 6;
    const int col = lane & 15, q = lane >> 4;

    f32x4 acc[4];
#pragma unroll
    for (int rt = 0; rt < 4; ++rt) acc[rt] = (f32x4){0.f, 0.f, 0.f, 0.f};

#pragma unroll 1
    for (int chunk = 0; chunk < 4; ++chunk) {
        __syncthreads();
        const float* src = (chunk == 0)
            ? x   + (size_t)n * 64 * 16384
            : cat + ((size_t)n * 192 + (chunk - 1) * 64) * 16384;
        for (int e = t; e < 6336; e += 256) {
            int cp  = e / 198;
            int rem = e % 198;
            int r   = rem / 66;
            int px  = rem % 66;
            int hh  = h + r - 1;
            int wp  = w0 + px - 1;
            unsigned v = 0;
            if ((unsigned)hh < 128u && (unsigned)wp < 128u) {
                const float* p = src + (size_t)(2 * cp) * 16384 + hh * 128 + wp;
                v = (unsigned)f2bf(p[0]) | ((unsigned)f2bf(p[16384]) << 16);
            }
            Xt[((r * 66 + px) * 32 + cp) ^ ((px & 7) << 2)] = v;
        }
        __syncthreads();

#pragma unroll
        for (int g = 0; g < 9; ++g) {
            const int kh = g / 3, kw = g % 3;
#pragma unroll
            for (int ks = 0; ks < 2; ++ks) {
                const int col_t = ctp * 16 + col + kw;
                unsigned byte = (unsigned)(((kh * 66 + col_t) * 32 + ks * 16 + q * 4) << 2)
                                ^ ((unsigned)(col_t & 7) << 4);
                s16x8 bf = *(const s16x8*)((const char*)Xt + byte);
                const unsigned short* ap =
                    fw3 + ((size_t)((((g * 4 + chunk) * 2 + ks) * 4) * 64 + lane)) * 8;
#pragma unroll
                for (int rt = 0; rt < 4; ++rt) {
                    s16x8 af = *(const s16x8*)(ap + (size_t)rt * 512);
                    acc[rt] = __builtin_amdgcn_mfma_f32_16x16x32_bf16(af, bf, acc[rt], 0, 0, 0);
                }
            }
        }
    }

    const int px = w0 + ctp * 16 + col;
#pragma unroll
    for (int rt = 0; rt < 4; ++rt) {
        f32x4 fb = *(const f32x4*)(fuse_b + rt * 16 + q * 4);
#pragma unroll
        for (int r = 0; r < 4; ++r) {
            int oc = rt * 16 + q * 4 + r;
            out[((size_t)n * 64 + oc) * 16384 + h * 128 + px] = acc[rt][r] + fb[r];
        }
    }
}

extern "C" void kernel_launch(void* const* d_in, const int* in_sizes, int n_in,
                              void* d_out, int out_size, void* d_ws, size_t ws_size,
                              hipStream_t stream) {
    const float* x      = (const float*)d_in[0];
    const float* y      = (const float*)d_in[1];
    const float* gen_w  = (const float*)d_in[2];
    const float* gen_b  = (const float*)d_in[3];
    const float* fuse_w = (const float*)d_in[4];
    const float* fuse_b = (const float*)d_in[5];
    float* out = (float*)d_out;
    float* ws  = (float*)d_ws;

    k_prep_wpk<<<dim3((13824 + 255) / 256), dim3(256), 0, stream>>>(
        gen_w, (unsigned short*)(ws + OFF_WPK));
    k_prep_gb<<<dim3(7), dim3(256), 0, stream>>>(gen_b, ws + OFF_GBP);
    k_prep_fw3<<<dim3((288 * 64 + 255) / 256), dim3(256), 0, stream>>>(
        fuse_w, (unsigned short*)(ws + OFF_FW3));
    k_gen_mfma<<<dim3(2, 128, 4), dim3(256), 0, stream>>>(
        x, y, (const unsigned short*)(ws + OFF_WPK), ws + OFF_GBP, ws + OFF_CAT);
    k_fuse_mfma<<<dim3(2, 128, 4), dim3(256), 0, stream>>>(
        x, ws + OFF_CAT, (const unsigned short*)(ws + OFF_FW3), fuse_b, out);
}

// Round 6
// 130.034 us; speedup vs baseline: 20.1877x; 1.2487x over previous
//
#include <hip/hip_runtime.h>

// Problem: N=4, C=64, H=W=128, KS=3, dilations {1,3,5}
// x[4,64,128,128] f32, y[same], gen_w[1728,64], gen_b[1728],
// fuse_w[64,256,3,3], fuse_b[64] -> out[4,64,128,128] f32.

using f32x4 = __attribute__((ext_vector_type(4))) float;
using u32x4 = __attribute__((ext_vector_type(4))) unsigned;
using s16x8 = __attribute__((ext_vector_type(8))) short;

// Workspace layout (float offsets)
#define OFF_WPK 0u         // gen_w A-frags bf16 [tap][tile12][ks2][lane][8] = 110592 bf16
#define OFF_FW3 55296u     // fuse_w A-frags bf16 [g][chunk][ks][rt][lane][8] = 147456 bf16
#define OFF_GBP 129024u    // gen_b fragment-order f32 [tap][tile12][row16]
#define OFF_XP  131072u    // x bf16-pairs u32 [n*32 planes][16384]
#define OFF_YP  2228224u   // y bf16-pairs u32 [n*32][16384]
#define OFF_CATP 4325376u  // cat bf16-pairs u32 [n*96][16384]
// end 10616832 floats (~42.5 MB)

__device__ __forceinline__ unsigned short f2bf(float f) {
    unsigned u = __builtin_bit_cast(unsigned, f);
    u = (u + 0x7fffu + ((u >> 16) & 1u)) >> 16;   // RNE
    return (unsigned short)u;
}
__device__ __forceinline__ float bflo(unsigned p) {
    return __builtin_bit_cast(float, p << 16);
}
__device__ __forceinline__ float bfhi(unsigned p) {
    return __builtin_bit_cast(float, p & 0xffff0000u);
}

// ---- prep: gen_w A-frags ----
__global__ void k_prep_wpk(const float* __restrict__ gen_w,
                           unsigned short* __restrict__ wpk) {
    int idx = blockIdx.x * 256 + threadIdx.x;
    if (idx >= 9 * 12 * 2 * 64) return;
    int lane = idx & 63;
    int r = idx >> 6;
    int ks = r & 1; r >>= 1;
    int tile = r % 12, tap = r / 12;
    int comb = tile * 16 + (lane & 15);
    int cc0  = ks * 32 + (lane >> 4) * 8;
    const float* src = gen_w + (size_t)(comb * 9 + tap) * 64 + cc0;
    unsigned short v[8];
#pragma unroll
    for (int j = 0; j < 8; ++j) v[j] = f2bf(src[j]);
    *(s16x8*)(wpk + (size_t)idx * 8) = *(const s16x8*)v;
}

// ---- prep: gen_b fragment order ----
__global__ void k_prep_gb(const float* __restrict__ gen_b,
                          float* __restrict__ gbp) {
    int idx = blockIdx.x * 256 + threadIdx.x;
    if (idx >= 1728) return;
    int row = idx & 15;
    int r = idx >> 4;
    int tile = r % 12, tap = r / 12;
    gbp[idx] = gen_b[(tile * 16 + row) * 9 + tap];
}

// ---- prep: fuse_w A-frags ----
__global__ void k_prep_fw3(const float* __restrict__ fuse_w,
                           unsigned short* __restrict__ fw3) {
    int idx = blockIdx.x * 256 + threadIdx.x;
    if (idx >= 288 * 64) return;
    int lane = idx & 63;
    int f = idx >> 6;
    int rt = f & 3; f >>= 2;
    int ks = f & 1; f >>= 1;
    int chunk = f & 3;
    int g = f >> 2;
    int oc = rt * 16 + (lane & 15);
    int ic = chunk * 64 + ks * 32 + (lane >> 4) * 8;
    const float* src = fuse_w + (size_t)oc * 2304 + (size_t)ic * 9 + g;
    unsigned short v[8];
#pragma unroll
    for (int j = 0; j < 8; ++j) v[j] = f2bf(src[j * 9]);
    *(s16x8*)(fw3 + (size_t)idx * 8) = *(const s16x8*)v;
}

// ---- prep: x,y -> bf16 channel-pair u32 arrays ----
__global__ void k_prep_xy(const float* __restrict__ x, const float* __restrict__ y,
                          unsigned* __restrict__ xp, unsigned* __restrict__ yp) {
    int idx = blockIdx.x * 256 + threadIdx.x;   // 1048576 total
    int a = idx >> 19;
    int rem = idx & 524287;
    int plane = rem >> 12;                      // n*32+cp, 0..127
    int hw4 = (rem & 4095) << 2;
    const float* src = a ? y : x;
    unsigned* dst = a ? yp : xp;
    const f32x4* s0 = (const f32x4*)(src + ((size_t)2 * plane) * 16384 + hw4);
    f32x4 v0 = s0[0];
    f32x4 v1 = s0[4096];
    unsigned o[4];
#pragma unroll
    for (int j = 0; j < 4; ++j)
        o[j] = (unsigned)f2bf(v0[j]) | ((unsigned)f2bf(v1[j]) << 16);
    *(u32x4*)(dst + (size_t)plane * 16384 + hw4) = *(const u32x4*)o;
}

// XCD-contiguous work decode: 1024 blocks = 8 XCD x 128; each XCD owns all
// 128 h-rows of one (n,strip) column -> h-halo re-reads hit that XCD's L2.
__device__ __forceinline__ void decode_wu(int id, int& h, int& w0, int& n) {
    int wu = (id & 7) * 128 + (id >> 3);
    h = wu & 127;
    int sn = wu >> 7;
    w0 = (sn & 1) << 6;
    n = sn >> 1;
}

// MFMA kernel-generation + in-register depthwise apply.
// Block = 64-px w-strip at (h,n). Wave wv owns comb tiles 3wv..3wv+2.
__global__ __launch_bounds__(256, 3) void k_gen_mfma(
    const unsigned* __restrict__ xp, const unsigned* __restrict__ yp,
    const unsigned short* __restrict__ wpk, const float* __restrict__ gbp,
    unsigned* __restrict__ catp)
{
    __shared__ __align__(16) unsigned Yt[2048]; // Y^T bf16-pairs, swizzled (8KB)

    int h, w0, n;
    decode_wu(blockIdx.x, h, w0, n);
    const int t = threadIdx.x;
    const int lane = t & 63;
    const int wv = t >> 6;
    const int q = lane >> 4, col = lane & 15;

    // stage Y^T: one u32 per (px,cp), coalesced over px=lane
    {
        const unsigned* yb = yp + (size_t)n * 32 * 16384 + h * 128 + w0 + lane;
#pragma unroll
        for (int p = 0; p < 8; ++p) {
            int cp = wv * 8 + p;
            Yt[(unsigned)(lane * 32 + cp) ^ (((unsigned)(lane & 7)) << 2)] =
                yb[(size_t)cp * 16384];
        }
    }
    __syncthreads();

    s16x8 bfr[4][2];
#pragma unroll
    for (int ctp = 0; ctp < 4; ++ctp)
#pragma unroll
        for (int ks = 0; ks < 2; ++ks) {
            int px = ctp * 16 + col;
            unsigned word = ((unsigned)(px * 32 + ks * 16 + q * 4)) ^
                            (((unsigned)(px & 7)) << 2);
            bfr[ctp][ks] = *(const s16x8*)(Yt + word);
        }

    const int tile0 = wv * 3;
    const unsigned* xn = xp + (size_t)n * 32 * 16384;

    float acc[3][4][4];
#pragma unroll
    for (int rt = 0; rt < 3; ++rt)
#pragma unroll
        for (int ctp = 0; ctp < 4; ++ctp)
#pragma unroll
            for (int r = 0; r < 4; ++r) acc[rt][ctp][r] = 0.f;

#pragma unroll 1
    for (int tap = 0; tap < 9; ++tap) {
        const int ti = tap / 3, tj = tap % 3;
        const unsigned short* wp = wpk + ((size_t)(tap * 12 + tile0) * 2 * 64 + lane) * 8;
#pragma unroll
        for (int rt = 0; rt < 3; ++rt) {
            const int tile = tile0 + rt;
            const int bi = tile >> 2;
            const int d  = 2 * bi + 1;
            const int hh = h + (ti - 1) * d;           // uniform
            const int cb = (tile & 3) * 16 + q * 4;    // channel base (even)

            f32x4 cinit = *(const f32x4*)(gbp + (size_t)(tap * 12 + tile) * 16 + q * 4);
            s16x8 a0 = *(const s16x8*)(wp + (size_t)(rt * 2 + 0) * 512);
            s16x8 a1 = *(const s16x8*)(wp + (size_t)(rt * 2 + 1) * 512);
#pragma unroll
            for (int ctp = 0; ctp < 4; ++ctp) {
                f32x4 kf = __builtin_amdgcn_mfma_f32_16x16x32_bf16(a0, bfr[ctp][0], cinit, 0, 0, 0);
                kf = __builtin_amdgcn_mfma_f32_16x16x32_bf16(a1, bfr[ctp][1], kf, 0, 0, 0);
                if (hh >= 0 && hh < 128) {
                    const int ww = w0 + ctp * 16 + col + (tj - 1) * d;
                    const bool inw = ((unsigned)ww < 128u);
                    const unsigned* xr = xn + (size_t)(cb >> 1) * 16384 + hh * 128 + ww;
                    unsigned p0 = inw ? xr[0] : 0u;
                    unsigned p1 = inw ? xr[16384] : 0u;
                    acc[rt][ctp][0] = fmaf(kf[0], bflo(p0), acc[rt][ctp][0]);
                    acc[rt][ctp][1] = fmaf(kf[1], bfhi(p0), acc[rt][ctp][1]);
                    acc[rt][ctp][2] = fmaf(kf[2], bflo(p1), acc[rt][ctp][2]);
                    acc[rt][ctp][3] = fmaf(kf[3], bfhi(p1), acc[rt][ctp][3]);
                }
            }
        }
    }

    // write cat as bf16 channel-pairs
    unsigned* cb0 = catp + (size_t)n * 96 * 16384 + h * 128;
#pragma unroll
    for (int rt = 0; rt < 3; ++rt) {
        const int combr = (tile0 + rt) * 16 + q * 4;   // even
#pragma unroll
        for (int ctp = 0; ctp < 4; ++ctp) {
            const int px = w0 + ctp * 16 + col;
            unsigned v0 = (unsigned)f2bf(acc[rt][ctp][0]) |
                          ((unsigned)f2bf(acc[rt][ctp][1]) << 16);
            unsigned v1 = (unsigned)f2bf(acc[rt][ctp][2]) |
                          ((unsigned)f2bf(acc[rt][ctp][3]) << 16);
            cb0[(size_t)((combr >> 1) + 0) * 16384 + px] = v0;
            cb0[(size_t)((combr >> 1) + 1) * 16384 + px] = v1;
        }
    }
}

// Fuse conv as bf16 MFMA GEMM: out[64 oc][64 px] per block.
__global__ __launch_bounds__(256) void k_fuse_mfma(
    const unsigned* __restrict__ xp, const unsigned* __restrict__ catp,
    const unsigned short* __restrict__ fw3, const float* __restrict__ fuse_b,
    float* __restrict__ out)
{
    __shared__ __align__(16) unsigned Xt[3 * 66 * 32];  // 25.3KB

    int h, w0, n;
    decode_wu(blockIdx.x, h, w0, n);
    const int t = threadIdx.x;
    const int lane = t & 63;
    const int ctp = t >> 6;
    const int col = lane & 15, q = lane >> 4;

    f32x4 acc[4];
#pragma unroll
    for (int rt = 0; rt < 4; ++rt) acc[rt] = (f32x4){0.f, 0.f, 0.f, 0.f};

#pragma unroll 1
    for (int chunk = 0; chunk < 4; ++chunk) {
        __syncthreads();
        const unsigned* src = (chunk == 0)
            ? xp   + (size_t)n * 32 * 16384
            : catp + ((size_t)n * 96 + (chunk - 1) * 32) * 16384;

        // interior: pow2 decode, coalesced 256B wave loads
#pragma unroll
        for (int e0 = 0; e0 < 6144; e0 += 256) {
            int e = e0 + t;
            int r  = e >> 11;
            int cp = (e >> 6) & 31;
            int px = e & 63;
            int hh = h + r - 1;
            unsigned v = 0;
            if ((unsigned)hh < 128u)
                v = src[(size_t)cp * 16384 + hh * 128 + w0 + px];
            int pt = px + 1;
            Xt[(unsigned)((r * 66 + pt) * 32 + cp) ^ (((unsigned)(pt & 7)) << 2)] = v;
        }
        // halo: px_t in {0,65}
        if (t < 192) {
            int r = t >> 6;
            int side = (t >> 5) & 1;
            int cp = t & 31;
            int pt = side ? 65 : 0;
            int wp = w0 + pt - 1;
            int hh = h + r - 1;
            unsigned v = 0;
            if ((unsigned)hh < 128u && (unsigned)wp < 128u)
                v = src[(size_t)cp * 16384 + hh * 128 + wp];
            Xt[(unsigned)((r * 66 + pt) * 32 + cp) ^ (((unsigned)(pt & 7)) << 2)] = v;
        }
        __syncthreads();

#pragma unroll
        for (int g = 0; g < 9; ++g) {
            const int kh = g / 3, kw = g % 3;
#pragma unroll
            for (int ks = 0; ks < 2; ++ks) {
                const int col_t = ctp * 16 + col + kw;
                unsigned word = ((unsigned)((kh * 66 + col_t) * 32 + ks * 16 + q * 4)) ^
                                (((unsigned)(col_t & 7)) << 2);
                s16x8 bf = *(const s16x8*)(Xt + word);
                const unsigned short* ap =
                    fw3 + ((size_t)((((g * 4 + chunk) * 2 + ks) * 4) * 64 + lane)) * 8;
#pragma unroll
                for (int rt = 0; rt < 4; ++rt) {
                    s16x8 af = *(const s16x8*)(ap + (size_t)rt * 512);
                    acc[rt] = __builtin_amdgcn_mfma_f32_16x16x32_bf16(af, bf, acc[rt], 0, 0, 0);
                }
            }
        }
    }

    const int px = w0 + ctp * 16 + col;
#pragma unroll
    for (int rt = 0; rt < 4; ++rt) {
        f32x4 fb = *(const f32x4*)(fuse_b + rt * 16 + q * 4);
#pragma unroll
        for (int r = 0; r < 4; ++r) {
            int oc = rt * 16 + q * 4 + r;
            out[((size_t)n * 64 + oc) * 16384 + h * 128 + px] = acc[rt][r] + fb[r];
        }
    }
}

extern "C" void kernel_launch(void* const* d_in, const int* in_sizes, int n_in,
                              void* d_out, int out_size, void* d_ws, size_t ws_size,
                              hipStream_t stream) {
    const float* x      = (const float*)d_in[0];
    const float* y      = (const float*)d_in[1];
    const float* gen_w  = (const float*)d_in[2];
    const float* gen_b  = (const float*)d_in[3];
    const float* fuse_w = (const float*)d_in[4];
    const float* fuse_b = (const float*)d_in[5];
    float* out = (float*)d_out;
    float* ws  = (float*)d_ws;

    unsigned* xp   = (unsigned*)(ws + OFF_XP);
    unsigned* yp   = (unsigned*)(ws + OFF_YP);
    unsigned* catp = (unsigned*)(ws + OFF_CATP);

    k_prep_wpk<<<dim3(54), dim3(256), 0, stream>>>(
        gen_w, (unsigned short*)(ws + OFF_WPK));
    k_prep_gb<<<dim3(7), dim3(256), 0, stream>>>(gen_b, ws + OFF_GBP);
    k_prep_fw3<<<dim3(72), dim3(256), 0, stream>>>(
        fuse_w, (unsigned short*)(ws + OFF_FW3));
    k_prep_xy<<<dim3(4096), dim3(256), 0, stream>>>(x, y, xp, yp);
    k_gen_mfma<<<dim3(1024), dim3(256), 0, stream>>>(
        xp, yp, (const unsigned short*)(ws + OFF_WPK), ws + OFF_GBP, catp);
    k_fuse_mfma<<<dim3(1024), dim3(256), 0, stream>>>(
        xp, catp, (const unsigned short*)(ws + OFF_FW3), fuse_b, out);
}

// Round 7
// 101.844 us; speedup vs baseline: 25.7755x; 1.2768x over previous
//
#include <hip/hip_runtime.h>

// Problem: N=4, C=64, H=W=128, KS=3, dilations {1,3,5}
// x[4,64,128,128] f32, y[same], gen_w[1728,64], gen_b[1728],
// fuse_w[64,256,3,3], fuse_b[64] -> out[4,64,128,128] f32.

using f32x4 = __attribute__((ext_vector_type(4))) float;
using u32x4 = __attribute__((ext_vector_type(4))) unsigned;
using s16x8 = __attribute__((ext_vector_type(8))) short;

// Workspace layout (float offsets)
#define OFF_WPK 0u         // gen_w A-frags bf16 [tap][tile12][ks2][lane][8] = 110592 bf16
#define OFF_FW3 55296u     // fuse_w A-frags bf16 [g][chunk][ks][rt][lane][8] = 147456 bf16
#define OFF_GBP 129024u    // gen_b fragment-order f32 [tap][tile12][row16]
#define OFF_XP  131072u    // x bf16-pairs u32 [n*32 planes][16384]
#define OFF_YP  2228224u   // y bf16-pairs u32 [n*32][16384]
#define OFF_CATP 4325376u  // cat bf16-pairs u32 [n*96][16384]
// end 10616832 floats (~42.5 MB)

__device__ __forceinline__ unsigned short f2bf(float f) {
    unsigned u = __builtin_bit_cast(unsigned, f);
    u = (u + 0x7fffu + ((u >> 16) & 1u)) >> 16;   // RNE
    return (unsigned short)u;
}
__device__ __forceinline__ float bflo(unsigned p) {
    return __builtin_bit_cast(float, p << 16);
}
__device__ __forceinline__ float bfhi(unsigned p) {
    return __builtin_bit_cast(float, p & 0xffff0000u);
}

// ---- prep: gen_w A-frags ----
__global__ void k_prep_wpk(const float* __restrict__ gen_w,
                           unsigned short* __restrict__ wpk) {
    int idx = blockIdx.x * 256 + threadIdx.x;
    if (idx >= 9 * 12 * 2 * 64) return;
    int lane = idx & 63;
    int r = idx >> 6;
    int ks = r & 1; r >>= 1;
    int tile = r % 12, tap = r / 12;
    int comb = tile * 16 + (lane & 15);
    int cc0  = ks * 32 + (lane >> 4) * 8;
    const float* src = gen_w + (size_t)(comb * 9 + tap) * 64 + cc0;
    unsigned short v[8];
#pragma unroll
    for (int j = 0; j < 8; ++j) v[j] = f2bf(src[j]);
    *(s16x8*)(wpk + (size_t)idx * 8) = *(const s16x8*)v;
}

// ---- prep: gen_b fragment order ----
__global__ void k_prep_gb(const float* __restrict__ gen_b,
                          float* __restrict__ gbp) {
    int idx = blockIdx.x * 256 + threadIdx.x;
    if (idx >= 1728) return;
    int row = idx & 15;
    int r = idx >> 4;
    int tile = r % 12, tap = r / 12;
    gbp[idx] = gen_b[(tile * 16 + row) * 9 + tap];
}

// ---- prep: fuse_w A-frags ----
__global__ void k_prep_fw3(const float* __restrict__ fuse_w,
                           unsigned short* __restrict__ fw3) {
    int idx = blockIdx.x * 256 + threadIdx.x;
    if (idx >= 288 * 64) return;
    int lane = idx & 63;
    int f = idx >> 6;
    int rt = f & 3; f >>= 2;
    int ks = f & 1; f >>= 1;
    int chunk = f & 3;
    int g = f >> 2;
    int oc = rt * 16 + (lane & 15);
    int ic = chunk * 64 + ks * 32 + (lane >> 4) * 8;
    const float* src = fuse_w + (size_t)oc * 2304 + (size_t)ic * 9 + g;
    unsigned short v[8];
#pragma unroll
    for (int j = 0; j < 8; ++j) v[j] = f2bf(src[j * 9]);
    *(s16x8*)(fw3 + (size_t)idx * 8) = *(const s16x8*)v;
}

// ---- prep: x,y -> bf16 channel-pair u32 arrays ----
__global__ void k_prep_xy(const float* __restrict__ x, const float* __restrict__ y,
                          unsigned* __restrict__ xp, unsigned* __restrict__ yp) {
    int idx = blockIdx.x * 256 + threadIdx.x;   // 1048576 total
    int a = idx >> 19;
    int rem = idx & 524287;
    int plane = rem >> 12;                      // n*32+cp, 0..127
    int hw4 = (rem & 4095) << 2;
    const float* src = a ? y : x;
    unsigned* dst = a ? yp : xp;
    const f32x4* s0 = (const f32x4*)(src + ((size_t)2 * plane) * 16384 + hw4);
    f32x4 v0 = s0[0];
    f32x4 v1 = s0[4096];
    unsigned o[4];
#pragma unroll
    for (int j = 0; j < 4; ++j)
        o[j] = (unsigned)f2bf(v0[j]) | ((unsigned)f2bf(v1[j]) << 16);
    *(u32x4*)(dst + (size_t)plane * 16384 + hw4) = *(const u32x4*)o;
}

// XCD-contiguous decode for k_gen (1024 blocks)
__device__ __forceinline__ void decode_wu(int id, int& h, int& w0, int& n) {
    int wu = (id & 7) * 128 + (id >> 3);
    h = wu & 127;
    int sn = wu >> 7;
    w0 = (sn & 1) << 6;
    n = sn >> 1;
}

// MFMA kernel-generation + in-register depthwise apply (unchanged from R6).
__global__ __launch_bounds__(256, 3) void k_gen_mfma(
    const unsigned* __restrict__ xp, const unsigned* __restrict__ yp,
    const unsigned short* __restrict__ wpk, const float* __restrict__ gbp,
    unsigned* __restrict__ catp)
{
    __shared__ __align__(16) unsigned Yt[2048];

    int h, w0, n;
    decode_wu(blockIdx.x, h, w0, n);
    const int t = threadIdx.x;
    const int lane = t & 63;
    const int wv = t >> 6;
    const int q = lane >> 4, col = lane & 15;

    {
        const unsigned* yb = yp + (size_t)n * 32 * 16384 + h * 128 + w0 + lane;
#pragma unroll
        for (int p = 0; p < 8; ++p) {
            int cp = wv * 8 + p;
            Yt[(unsigned)(lane * 32 + cp) ^ (((unsigned)(lane & 7)) << 2)] =
                yb[(size_t)cp * 16384];
        }
    }
    __syncthreads();

    s16x8 bfr[4][2];
#pragma unroll
    for (int ctp = 0; ctp < 4; ++ctp)
#pragma unroll
        for (int ks = 0; ks < 2; ++ks) {
            int px = ctp * 16 + col;
            unsigned word = ((unsigned)(px * 32 + ks * 16 + q * 4)) ^
                            (((unsigned)(px & 7)) << 2);
            bfr[ctp][ks] = *(const s16x8*)(Yt + word);
        }

    const int tile0 = wv * 3;
    const unsigned* xn = xp + (size_t)n * 32 * 16384;

    float acc[3][4][4];
#pragma unroll
    for (int rt = 0; rt < 3; ++rt)
#pragma unroll
        for (int ctp = 0; ctp < 4; ++ctp)
#pragma unroll
            for (int r = 0; r < 4; ++r) acc[rt][ctp][r] = 0.f;

#pragma unroll 1
    for (int tap = 0; tap < 9; ++tap) {
        const int ti = tap / 3, tj = tap % 3;
        const unsigned short* wp = wpk + ((size_t)(tap * 12 + tile0) * 2 * 64 + lane) * 8;
#pragma unroll
        for (int rt = 0; rt < 3; ++rt) {
            const int tile = tile0 + rt;
            const int bi = tile >> 2;
            const int d  = 2 * bi + 1;
            const int hh = h + (ti - 1) * d;
            const int cb = (tile & 3) * 16 + q * 4;

            f32x4 cinit = *(const f32x4*)(gbp + (size_t)(tap * 12 + tile) * 16 + q * 4);
            s16x8 a0 = *(const s16x8*)(wp + (size_t)(rt * 2 + 0) * 512);
            s16x8 a1 = *(const s16x8*)(wp + (size_t)(rt * 2 + 1) * 512);
#pragma unroll
            for (int ctp = 0; ctp < 4; ++ctp) {
                f32x4 kf = __builtin_amdgcn_mfma_f32_16x16x32_bf16(a0, bfr[ctp][0], cinit, 0, 0, 0);
                kf = __builtin_amdgcn_mfma_f32_16x16x32_bf16(a1, bfr[ctp][1], kf, 0, 0, 0);
                if (hh >= 0 && hh < 128) {
                    const int ww = w0 + ctp * 16 + col + (tj - 1) * d;
                    const bool inw = ((unsigned)ww < 128u);
                    const unsigned* xr = xn + (size_t)(cb >> 1) * 16384 + hh * 128 + ww;
                    unsigned p0 = inw ? xr[0] : 0u;
                    unsigned p1 = inw ? xr[16384] : 0u;
                    acc[rt][ctp][0] = fmaf(kf[0], bflo(p0), acc[rt][ctp][0]);
                    acc[rt][ctp][1] = fmaf(kf[1], bfhi(p0), acc[rt][ctp][1]);
                    acc[rt][ctp][2] = fmaf(kf[2], bflo(p1), acc[rt][ctp][2]);
                    acc[rt][ctp][3] = fmaf(kf[3], bfhi(p1), acc[rt][ctp][3]);
                }
            }
        }
    }

    unsigned* cb0 = catp + (size_t)n * 96 * 16384 + h * 128;
#pragma unroll
    for (int rt = 0; rt < 3; ++rt) {
        const int combr = (tile0 + rt) * 16 + q * 4;
#pragma unroll
        for (int ctp = 0; ctp < 4; ++ctp) {
            const int px = w0 + ctp * 16 + col;
            unsigned v0 = (unsigned)f2bf(acc[rt][ctp][0]) |
                          ((unsigned)f2bf(acc[rt][ctp][1]) << 16);
            unsigned v1 = (unsigned)f2bf(acc[rt][ctp][2]) |
                          ((unsigned)f2bf(acc[rt][ctp][3]) << 16);
            cb0[(size_t)((combr >> 1) + 0) * 16384 + px] = v0;
            cb0[(size_t)((combr >> 1) + 1) * 16384 + px] = v1;
        }
    }
}

// Fuse conv, v2: 2 output rows per block, grid 512 (= 8 XCD x 64 h-units).
// Block 256 = 4 waves; wave = 16-px tile ctp, computes rows h0,h0+1 x 64 oc.
// LDS Xt[r4][cp32][68]: interior via b128 writes (conflict-free), reg-prefetch.
__global__ __launch_bounds__(256) void k_fuse_mfma(
    const unsigned* __restrict__ xp, const unsigned* __restrict__ catp,
    const unsigned short* __restrict__ fw3, const float* __restrict__ fuse_b,
    float* __restrict__ out)
{
    __shared__ __align__(16) unsigned Xt[4 * 32 * 68];  // 34.8 KB

    const int id = blockIdx.x;
    const int xcd = id & 7;
    const int unit = id >> 3;
    const int n  = xcd >> 1;
    const int w0 = (xcd & 1) << 6;
    const int h0 = unit << 1;

    const int t = threadIdx.x;
    const int lane = t & 63;
    const int ctp = t >> 6;            // wave-uniform
    const int col = lane & 15, q = lane >> 4;

    // staging decode (constant per thread): 8 interior tasks + 1 halo task
    int s_r[8], s_cp[8], s_li[8];
#pragma unroll
    for (int it = 0; it < 8; ++it) {
        int e = it * 256 + t;
        s_r[it]  = e >> 9;
        s_cp[it] = (e >> 4) & 31;
        s_li[it] = e & 15;
    }
    const int hr = t >> 6, hcp = (t >> 1) & 31, hside = t & 1;  // halo: 256 tasks
    const int hpx = hside ? (w0 + 64) : (w0 - 1);
    const bool hok = ((unsigned)hpx < 128u);

    // per-lane B-read column indices (g-invariant, one per kw)
    const int bcol = ctp * 16 + col;
    const int m_kw[3] = { (bcol == 0) ? 64 : bcol - 1,
                          bcol,
                          (bcol == 63) ? 65 : bcol + 1 };

    f32x4 acc[2][4];
#pragma unroll
    for (int row = 0; row < 2; ++row)
#pragma unroll
        for (int rt = 0; rt < 4; ++rt) acc[row][rt] = (f32x4){0.f, 0.f, 0.f, 0.f};

    const unsigned* srcs[4] = {
        xp   + (size_t)n * 32 * 16384,
        catp + (size_t)n * 96 * 16384,
        catp + ((size_t)n * 96 + 32) * 16384,
        catp + ((size_t)n * 96 + 64) * 16384 };

    // ---- prefetch chunk 0 ----
    u32x4 pf[8];
    unsigned pfh;
    {
        const unsigned* src = srcs[0];
#pragma unroll
        for (int it = 0; it < 8; ++it) {
            int hh = h0 - 1 + s_r[it];
            pf[it] = (u32x4){0u, 0u, 0u, 0u};
            if ((unsigned)hh < 128u)
                pf[it] = *(const u32x4*)(src + (size_t)s_cp[it] * 16384 + hh * 128 + w0 + s_li[it] * 4);
        }
        int hh = h0 - 1 + hr;
        pfh = 0u;
        if (((unsigned)hh < 128u) && hok)
            pfh = src[(size_t)hcp * 16384 + hh * 128 + hpx];
    }

#pragma unroll 1
    for (int chunk = 0; chunk < 4; ++chunk) {
        // ---- write staged regs to LDS ----
#pragma unroll
        for (int it = 0; it < 8; ++it)
            *(u32x4*)(Xt + (s_r[it] * 32 + s_cp[it]) * 68 + s_li[it] * 4) = pf[it];
        Xt[(hr * 32 + hcp) * 68 + 64 + hside] = pfh;

        // ---- prefetch next chunk while computing this one ----
        if (chunk < 3) {
            const unsigned* src = srcs[chunk + 1];
#pragma unroll
            for (int it = 0; it < 8; ++it) {
                int hh = h0 - 1 + s_r[it];
                u32x4 v = (u32x4){0u, 0u, 0u, 0u};
                if ((unsigned)hh < 128u)
                    v = *(const u32x4*)(src + (size_t)s_cp[it] * 16384 + hh * 128 + w0 + s_li[it] * 4);
                pf[it] = v;
            }
            int hh = h0 - 1 + hr;
            unsigned v = 0u;
            if (((unsigned)hh < 128u) && hok)
                v = src[(size_t)hcp * 16384 + hh * 128 + hpx];
            pfh = v;
        }
        __syncthreads();

        // ---- compute: 9 taps x 2 ks x (2 rows x 4 rt) MFMA ----
#pragma unroll
        for (int g = 0; g < 9; ++g) {
            const int kh = g / 3, kw = g % 3;
            const int mm = m_kw[kw];
#pragma unroll
            for (int ks = 0; ks < 2; ++ks) {
                const int cpb = ks * 16 + q * 4;
                s16x8 bf[2];
#pragma unroll
                for (int row = 0; row < 2; ++row) {
                    const unsigned* bp = Xt + ((row + kh) * 32 + cpb) * 68 + mm;
                    unsigned b0 = bp[0], b1 = bp[68], b2 = bp[136], b3 = bp[204];
                    unsigned bb[4] = {b0, b1, b2, b3};
                    bf[row] = *(const s16x8*)bb;
                }
                const unsigned short* ap =
                    fw3 + ((size_t)((((g * 4 + chunk) * 2 + ks) * 4) * 64 + lane)) * 8;
#pragma unroll
                for (int rt = 0; rt < 4; ++rt) {
                    s16x8 af = *(const s16x8*)(ap + (size_t)rt * 512);
#pragma unroll
                    for (int row = 0; row < 2; ++row)
                        acc[row][rt] = __builtin_amdgcn_mfma_f32_16x16x32_bf16(
                            af, bf[row], acc[row][rt], 0, 0, 0);
                }
            }
        }
        __syncthreads();
    }

    const int px = w0 + ctp * 16 + col;
#pragma unroll
    for (int rt = 0; rt < 4; ++rt) {
        f32x4 fb = *(const f32x4*)(fuse_b + rt * 16 + q * 4);
#pragma unroll
        for (int row = 0; row < 2; ++row)
#pragma unroll
            for (int r = 0; r < 4; ++r) {
                int oc = rt * 16 + q * 4 + r;
                out[((size_t)n * 64 + oc) * 16384 + (h0 + row) * 128 + px] =
                    acc[row][rt][r] + fb[r];
            }
    }
}

extern "C" void kernel_launch(void* const* d_in, const int* in_sizes, int n_in,
                              void* d_out, int out_size, void* d_ws, size_t ws_size,
                              hipStream_t stream) {
    const float* x      = (const float*)d_in[0];
    const float* y      = (const float*)d_in[1];
    const float* gen_w  = (const float*)d_in[2];
    const float* gen_b  = (const float*)d_in[3];
    const float* fuse_w = (const float*)d_in[4];
    const float* fuse_b = (const float*)d_in[5];
    float* out = (float*)d_out;
    float* ws  = (float*)d_ws;

    unsigned* xp   = (unsigned*)(ws + OFF_XP);
    unsigned* yp   = (unsigned*)(ws + OFF_YP);
    unsigned* catp = (unsigned*)(ws + OFF_CATP);

    k_prep_wpk<<<dim3(54), dim3(256), 0, stream>>>(
        gen_w, (unsigned short*)(ws + OFF_WPK));
    k_prep_gb<<<dim3(7), dim3(256), 0, stream>>>(gen_b, ws + OFF_GBP);
    k_prep_fw3<<<dim3(72), dim3(256), 0, stream>>>(
        fuse_w, (unsigned short*)(ws + OFF_FW3));
    k_prep_xy<<<dim3(4096), dim3(256), 0, stream>>>(x, y, xp, yp);
    k_gen_mfma<<<dim3(1024), dim3(256), 0, stream>>>(
        xp, yp, (const unsigned short*)(ws + OFF_WPK), ws + OFF_GBP, catp);
    k_fuse_mfma<<<dim3(512), dim3(256), 0, stream>>>(
        xp, catp, (const unsigned short*)(ws + OFF_FW3), fuse_b, out);
}